// Round 5
// baseline (106.915 us; speedup 1.0000x reference)
//
#include <hip/hip_runtime.h>
#include <math.h>

// Problem constants
#define NPIX    65536     // 64*32*32 pixels
#define NELEM   655360    // 64*10*32*32 elements of z
#define NCODE   1024
#define CSTRIDE 1024      // stride between channels in z (h*w)
#define BSTRIDE 10240     // stride between batches in z (c*h*w)
#define NBLK    1024      // k_pixel blocks: 4 lanes/pixel, 64 pixels/block
#define NHB     32        // k_hist blocks

// Any code flipping a channel with |v| > SOFT_T has exp(t) == 0 in fp32
// (t < -88 underflows), matching the reference's own fp32 softmax.
#define SOFT_T 0.22f

// d_ws float offsets (everything below is written unconditionally each call,
// so NO memset is needed despite 0xAA poisoning):
#define WS_HIST 0                         // [0, 1024*1024): per-block hist copies
#define WS_PLP  (NBLK * NCODE)            // [WS_PLP, +1024): per-block plogp sums
#define WS_COM  (WS_PLP + NBLK)           // [WS_COM, +1024): per-block commit sums
#define WS_ENT  (WS_COM + NBLK)           // [WS_ENT, +32):   per-k_hist-block entropy

// d_out layout (floats):
//   [0, 655360)        z_q_out (sign(z), b,c,h,w like z)
//   [655360..655364]   loss, commit, ent_loss, per_sample_entropy, avg_entropy
//   [655365, 720901)   min_encoding_indices (as float), [b,h,w]

__global__ void __launch_bounds__(256)
k_pixel(const float* __restrict__ z,
        float* __restrict__ zq,
        float* __restrict__ out_idx,
        float* __restrict__ ws) {
    __shared__ float hist[NCODE];
    __shared__ uint2 s_e[64 * 11];        // per-PIXEL soft table (|v|, chan bit)
    __shared__ float2 red[256];

    int tid = threadIdx.x;
    for (int i = tid; i < NCODE; i += 256) hist[i] = 0.f;

    // --- grid-stride signs + commit: dense, full-line coalesced stores ---
    float commit = 0.f;
    {
        int i0 = blockIdx.x * 256 + tid;          // 262144 threads total
        float x = z[i0];
        float h = (x > 0.f) ? 1.f : -1.f;
        zq[i0] = h; float d = h - x; commit = fmaf(d, d, commit);
        int i1 = i0 + 262144;
        x = z[i1]; h = (x > 0.f) ? 1.f : -1.f;
        zq[i1] = h; d = h - x; commit = fmaf(d, d, commit);
        int i2 = i1 + 262144;
        if (i2 < NELEM) {
            x = z[i2]; h = (x > 0.f) ? 1.f : -1.f;
            zq[i2] = h; d = h - x; commit = fmaf(d, d, commit);
        }
    }
    __syncthreads();                               // hist init visible

    // --- per-pixel softmax stats (product form), 4 lanes per pixel ---
    int p   = blockIdx.x * 64 + (tid >> 2);        // pixel id: b*1024 + h*32 + w
    int sub = tid & 3;
    int b = p >> 10;
    int hw = p & 1023;
    const float* zp = z + b * BSTRIDE + hw;
    uint2* et = &s_e[(tid >> 2) * 11];             // 4 lanes write identical data

    int idx = 0, k = 0;
    float Z = 1.f, W = 0.f;
#pragma unroll
    for (int c = 0; c < 10; ++c) {
        float x = zp[c * CSTRIDE];
        if (x > 0.f) idx |= (1 << c);
        float a = fabsf(x);
        float t = -400.f * a;
        float e = __expf(t);
        Z *= (1.f + e);
        W = fmaf(t, e / (1.f + e), W);
        if (a < SOFT_T) {
            uint2 u; u.x = __float_as_uint(a); u.y = 1u << c;
            et[k] = u; ++k;
        }
    }
    if (sub == 0) out_idx[p] = (float)idx;
    float invZ = 1.f / Z;
    float plogp = W - logf(Z);                     // sum_n p_n log p_n

    // --- histogram pass: lane `sub` takes subsets with top-2 soft bits == sub ---
    float s0 = 0.f; unsigned cm0 = 0;
    bool active; int nIter;
    if (k >= 2) {
        active = true;
        nIter = 1 << (k - 2);
        if (sub & 1) { uint2 u = et[k - 1]; s0 += __uint_as_float(u.x); cm0 ^= u.y; }
        if (sub & 2) { uint2 u = et[k - 2]; s0 += __uint_as_float(u.x); cm0 ^= u.y; }
    } else {
        active = sub < (1 << k);
        nIter = 1;
        if (k == 1 && sub == 1) { uint2 u = et[0]; s0 = __uint_as_float(u.x); cm0 = u.y; }
    }
    if (active) {
        atomicAdd(&hist[idx ^ cm0], __expf(-400.f * s0) * invZ);
        int gray = 0; float s = s0; unsigned cmask = cm0;
        for (int m = 1; m < nIter; ++m) {
            int bit = __ffs(m) - 1;                // Gray code: flip entry `bit`
            uint2 u = et[bit];
            int bm = 1 << bit;
            gray ^= bm;
            float a = __uint_as_float(u.x);
            s += (gray & bm) ? a : -a;
            cmask ^= u.y;
            atomicAdd(&hist[idx ^ cmask], __expf(-400.f * s) * invZ);
        }
    }

    // --- block-reduce (plogp once per pixel, commit) ---
    red[tid] = make_float2((sub == 0) ? plogp : 0.f, commit);
    __syncthreads();
    for (int st = 128; st > 0; st >>= 1) {
        if (tid < st) {
            red[tid].x += red[tid + st].x;
            red[tid].y += red[tid + st].y;
        }
        __syncthreads();
    }
    if (tid == 0) {
        ws[WS_PLP + blockIdx.x] = red[0].x;
        ws[WS_COM + blockIdx.x] = red[0].y;
    }

    // --- flush private hist copy: plain coalesced stores, no atomics ---
    float* hc = ws + WS_HIST + (size_t)blockIdx.x * NCODE;
    for (int i = tid; i < NCODE; i += 256) hc[i] = hist[i];
}

__global__ void __launch_bounds__(256)
k_hist(const float* __restrict__ ws, float* __restrict__ ws_w) {
    __shared__ float sh[256];
    int bin0 = blockIdx.x * 32;                    // 32 bins per block
    int bin = threadIdx.x & 31;
    int grp = threadIdx.x >> 5;                    // 8 copy-groups
    float acc = 0.f;
    for (int c = grp; c < NBLK; c += 8)
        acc += ws[WS_HIST + (size_t)c * NCODE + bin0 + bin];
    sh[threadIdx.x] = acc;
    __syncthreads();
    if (threadIdx.x < 32) {
        float a = sh[bin];
#pragma unroll
        for (int g = 1; g < 8; ++g) a += sh[g * 32 + bin];
        a *= (1.f / 65536.f);                      // avg_probs[bin0+bin]
        float ent = -a * logf(a + 1e-5f);
        for (int off = 16; off > 0; off >>= 1)
            ent += __shfl_down(ent, off, 32);
        if (bin == 0) ws_w[WS_ENT + blockIdx.x] = ent;
    }
}

__global__ void __launch_bounds__(256)
k_scalars(const float* __restrict__ ws, float* __restrict__ out_sc) {
    __shared__ float2 red[256];
    int t = threadIdx.x;
    float plp = 0.f, com = 0.f;
#pragma unroll
    for (int j = 0; j < 4; ++j) {
        plp += ws[WS_PLP + t + j * 256];
        com += ws[WS_COM + t + j * 256];
    }
    red[t] = make_float2(plp, com);
    __syncthreads();
    for (int st = 128; st > 0; st >>= 1) {
        if (t < st) {
            red[t].x += red[t + st].x;
            red[t].y += red[t + st].y;
        }
        __syncthreads();
    }
    if (t == 0) {
        float avg_entropy = 0.f;
        for (int g = 0; g < NHB; ++g) avg_entropy += ws[WS_ENT + g];
        float pse = -red[0].x * (1.f / 65536.f);   // per_sample_entropy
        float cl  = 0.25f * red[0].y * (1.f / (float)NELEM);
        float el  = 0.1f * (pse - avg_entropy);
        out_sc[0] = cl + el;                       // loss
        out_sc[1] = cl;
        out_sc[2] = el;
        out_sc[3] = pse;
        out_sc[4] = avg_entropy;
    }
}

extern "C" void kernel_launch(void* const* d_in, const int* in_sizes, int n_in,
                              void* d_out, int out_size, void* d_ws, size_t ws_size,
                              hipStream_t stream) {
    const float* z = (const float*)d_in[0];
    float* out = (float*)d_out;
    float* ws = (float*)d_ws;

    k_pixel<<<NBLK, 256, 0, stream>>>(z, out, out + NELEM + 5, ws);
    k_hist<<<NHB, 256, 0, stream>>>(ws, ws);
    k_scalars<<<1, 256, 0, stream>>>(ws, out + NELEM);
}

// Round 6
// 73.074 us; speedup vs baseline: 1.4631x; 1.4631x over previous
//
#include <hip/hip_runtime.h>
#include <math.h>

// Problem constants
#define NPIX    65536     // 64*32*32 pixels
#define NELEM   655360    // 64*10*32*32 elements of z
#define NCODE   1024
#define CSTRIDE 1024      // stride between channels in z (h*w)
#define BSTRIDE 10240     // stride between batches in z (c*h*w)
#define NBLK    256       // k_pixel blocks: 1 thread/pixel (R4 mapping — best known)
#define NHB     16        // k_hist blocks

// Any code flipping a channel with |v| > SOFT_T has exp(t) == 0 in fp32
// (t < -88 underflows), matching the reference's own fp32 softmax.
#define SOFT_T 0.22f

// d_ws float offsets. Every word below is unconditionally written each call,
// so NO memset node is needed despite 0xAA poisoning.
#define WS_HIST 0                        // [0, 256*1024): per-block hist copies
#define WS_PLP  (NBLK * NCODE)           // +256: per-block plogp sums
#define WS_COM  (WS_PLP + NBLK)          // +256: per-block commit sums
#define WS_ENT  (WS_COM + NBLK)          // +16:  per-k_hist-block entropy partials

// d_out layout (floats):
//   [0, 655360)        z_q_out (sign(z), b,c,h,w like z)
//   [655360..655364]   loss, commit, ent_loss, per_sample_entropy, avg_entropy
//   [655365, 720901)   min_encoding_indices (as float), [b,h,w]

__global__ void __launch_bounds__(256)
k_pixel(const float* __restrict__ z,
        float* __restrict__ zq,
        float* __restrict__ out_idx,
        float* __restrict__ ws) {
    __shared__ float hist[NCODE];
    __shared__ uint2 s_e[256 * 11];   // per-thread soft table: (|v| bits, chan bitmask)
    __shared__ float2 red[256];

    int tid = threadIdx.x;
    for (int i = tid; i < NCODE; i += 256) hist[i] = 0.f;
    __syncthreads();

    int p = blockIdx.x * 256 + tid;   // pixel id: b*1024 + h*32 + w
    int b = p >> 10;
    int hw = p & 1023;
    const float* zp = z  + b * BSTRIDE + hw;
    float*       qp = zq + b * BSTRIDE + hw;
    uint2* et = &s_e[tid * 11];

    // --- per-pixel: signs, commit, index, PRODUCT-FORM softmax stats ---
    // Z = prod_c (1 + e_c),  sum_n p log p = sum_c t_c*e_c/(1+e_c) - log Z,
    // e_c = exp(-400*|v_c|).  Exact: hard channels give e_c == 0 in fp32.
    int idx = 0, k = 0;
    float commit = 0.f;
    float Z = 1.f, W = 0.f;
#pragma unroll
    for (int c = 0; c < 10; ++c) {
        float x = zp[c * CSTRIDE];
        float h = (x > 0.f) ? 1.f : -1.f;
        qp[c * CSTRIDE] = h;                       // dense, coalesced stores
        float d = h - x;
        commit = fmaf(d, d, commit);
        if (x > 0.f) idx |= (1 << c);
        float a = fabsf(x);
        float t = -400.f * a;
        float e = __expf(t);
        float op = 1.f + e;
        Z *= op;
        W = fmaf(t, e * __builtin_amdgcn_rcpf(op), W);
        if (a < SOFT_T) {
            uint2 u; u.x = __float_as_uint(a); u.y = 1u << c;
            et[k] = u; ++k;
        }
    }
    out_idx[p] = (float)idx;
    float invZ = __builtin_amdgcn_rcpf(Z);
    float plogp = W - __logf(Z);                   // sum_n p_n log p_n  (<=0)

    // --- pass 2: histogram over soft-channel subsets (Gray code, prefetched) ---
    int nsub = 1 << k;
    atomicAdd(&hist[idx], invZ);                   // empty subset: p = 1/Z
    float s = 0.f;
    int gray = 0;
    unsigned cmask = 0;
    uint2 cur = et[0];                             // bit(m=1) == 0
    for (int m = 1; m < nsub; ++m) {
        int nbit = __ffs(m + 1) - 1;
        uint2 nxt = et[nbit];                      // prefetch next entry
        int bm = 1 << (__ffs(m) - 1);
        gray ^= bm;
        float a = __uint_as_float(cur.x);
        s += (gray & bm) ? a : -a;
        cmask ^= cur.y;
        atomicAdd(&hist[idx ^ cmask], __expf(-400.f * s) * invZ);
        cur = nxt;
    }

    // --- block-reduce (plogp, commit) ---
    red[tid] = make_float2(plogp, commit);
    __syncthreads();
    for (int st = 128; st > 0; st >>= 1) {
        if (tid < st) {
            red[tid].x += red[tid + st].x;
            red[tid].y += red[tid + st].y;
        }
        __syncthreads();
    }
    if (tid == 0) {
        ws[WS_PLP + blockIdx.x] = red[0].x;
        ws[WS_COM + blockIdx.x] = red[0].y;
    }

    // --- flush private hist copy: float4 coalesced stores, NO atomics ---
    float4* hc = (float4*)(ws + WS_HIST + (size_t)blockIdx.x * NCODE);
    float4* hs = (float4*)hist;
    hc[tid] = hs[tid];                             // 256 threads x 16B = 4KB
}

// 16 blocks x 1024 threads: block b reduces bins [b*64, b*64+64) over 256 copies.
__global__ void __launch_bounds__(1024)
k_hist(const float* __restrict__ ws, float* __restrict__ ws_w) {
    __shared__ float sh[16 * 64];
    int t = threadIdx.x;
    int lane = t & 63;
    int w = t >> 6;                                // 16 copy-groups
    int bin = blockIdx.x * 64 + lane;
    float acc = 0.f;
#pragma unroll 4
    for (int c = w; c < NBLK; c += 16)
        acc += ws[WS_HIST + (size_t)c * NCODE + bin];   // 256B coalesced per wave
    sh[w * 64 + lane] = acc;
    __syncthreads();
    if (t < 64) {
        float a = sh[lane];
#pragma unroll
        for (int g = 1; g < 16; ++g) a += sh[g * 64 + lane];
        a *= (1.f / 65536.f);                      // avg_probs[bin]
        float ent = -a * __logf(a + 1e-5f);
#pragma unroll
        for (int off = 32; off > 0; off >>= 1)
            ent += __shfl_down(ent, off, 64);
        if (lane == 0) ws_w[WS_ENT + blockIdx.x] = ent;
    }
}

__global__ void __launch_bounds__(256)
k_scalars(const float* __restrict__ ws, float* __restrict__ out_sc) {
    __shared__ float2 red[256];
    int t = threadIdx.x;
    red[t] = make_float2(ws[WS_PLP + t], ws[WS_COM + t]);
    __syncthreads();
    for (int st = 128; st > 0; st >>= 1) {
        if (t < st) {
            red[t].x += red[t + st].x;
            red[t].y += red[t + st].y;
        }
        __syncthreads();
    }
    if (t == 0) {
        float avg_entropy = 0.f;
#pragma unroll
        for (int g = 0; g < NHB; ++g) avg_entropy += ws[WS_ENT + g];
        float pse = -red[0].x * (1.f / 65536.f);   // per_sample_entropy
        float cl  = 0.25f * red[0].y * (1.f / (float)NELEM);
        float el  = 0.1f * (pse - avg_entropy);
        out_sc[0] = cl + el;                       // loss
        out_sc[1] = cl;
        out_sc[2] = el;
        out_sc[3] = pse;
        out_sc[4] = avg_entropy;
    }
}

extern "C" void kernel_launch(void* const* d_in, const int* in_sizes, int n_in,
                              void* d_out, int out_size, void* d_ws, size_t ws_size,
                              hipStream_t stream) {
    const float* z = (const float*)d_in[0];
    float* out = (float*)d_out;
    float* ws = (float*)d_ws;

    k_pixel<<<NBLK, 256, 0, stream>>>(z, out, out + NELEM + 5, ws);
    k_hist<<<NHB, 1024, 0, stream>>>(ws, ws);
    k_scalars<<<1, 256, 0, stream>>>(ws, out + NELEM);
}